// Round 5
// baseline (75.251 us; speedup 1.0000x reference)
//
#include <hip/hip_runtime.h>
#include <hip/hip_bf16.h>
#include <math.h>

#define B_ 16
#define L_ 2048
#define H_ 1024
#define A_ 1024
#define C_ 5

#define NSPLIT 4                 // A-dim split across blocks in MFMA part
#define MT 64                    // rows per tile
#define NTB 256                  // a-cols per block
#define KT 64                    // k-step
#define TPB 8                    // tiles per batch (8*64=512 >= max masked count 511)
#define KC_BLOCKS (B_ * TPB * NSPLIT)   // 512 MFMA blocks
#define KE_BLOCKS (B_ * L_ / 4)         // 8192 streaming blocks (4 rows each)
#define KW_BLOCKS (A_ * H_ / (256 * 8)) // 512 W-convert blocks

typedef __attribute__((ext_vector_type(8))) short short8v;
typedef __attribute__((ext_vector_type(4))) float float4v;

// ---- workspace layout (bytes) ----
static constexpr size_t OFF_SCAL   = 0;        // 2 f: denom, wsum
static constexpr size_t OFF_END    = 64;       // B ints
static constexpr size_t OFF_CNT    = 192;      // B ints
static constexpr size_t OFF_STARTS = 320;      // B*C ints
static constexpr size_t OFF_LIST   = 4096;                              // B*L ints
static constexpr size_t OFF_W16    = OFF_LIST + (size_t)B_ * L_ * 4;    // A*H bf16
static constexpr size_t OFF_PP     = OFF_W16 + (size_t)A_ * H_ * 2;     // NSPLIT*B*L f
static constexpr size_t OFF_D      = OFF_PP + (size_t)NSPLIT * B_ * L_ * 4;  // B*L f

static __device__ __forceinline__ unsigned short f2bf(float f) {
  unsigned u = __float_as_uint(f);
  unsigned r = (u >> 16) & 1u;
  return (unsigned short)((u + 0x7fffu + r) >> 16);
}

// ============ kernel 1: kWA — masks + scalars + W f32->bf16 ============
__global__ __launch_bounds__(256) void kWA(const int* __restrict__ attn,
                                           const int* __restrict__ mlm,
                                           const float* __restrict__ query,
                                           const float* __restrict__ Wcls,
                                           const float* __restrict__ Wh,
                                           float* __restrict__ ws_scal,
                                           int* __restrict__ endv,
                                           int* __restrict__ cnt,
                                           int* __restrict__ starts,
                                           int* __restrict__ list,
                                           unsigned short* __restrict__ W16) {
  __shared__ int   wsh[4];
  __shared__ float sf1[256];
  __shared__ float sf2[256];
  const int bid = blockIdx.x;
  const int t = threadIdx.x;

  if (bid < B_) {
    const int b = bid;
    const int* arow = attn + (size_t)b * L_;
    const int* mrow = mlm + (size_t)b * L_;
    const int w = t >> 6;
    const int lane = t & 63;
    const int base = t * 8;

    // ---- pass 1: attn==0 compaction (ascending) ----
    int loc[8];
    int lc = 0;
#pragma unroll
    for (int j = 0; j < 8; ++j) {
      int l = base + j;
      if (arow[l] == 0) loc[lc++] = l;
    }
    int incl = lc;
#pragma unroll
    for (int o = 1; o < 64; o <<= 1) {
      int v = __shfl_up(incl, o, 64);
      if (lane >= o) incl += v;
    }
    if (lane == 63) wsh[w] = incl;
    __syncthreads();
    int pre = 0, total = 0;
#pragma unroll
    for (int i = 0; i < 4; ++i) {
      int s = wsh[i];
      if (i < w) pre += s;
      total += s;
    }
    int excl = pre + incl - lc;
    int* lrow = list + (size_t)b * L_;
    for (int j = 0; j < lc; ++j) lrow[excl + j] = loc[j];
    if (t == 0) {
      cnt[b] = total;
      endv[b] = L_ - total;
    }
    __syncthreads();

    // ---- pass 2: mlm>0 markers ----
    int mloc[8];
    int mc = 0;
#pragma unroll
    for (int j = 0; j < 8; ++j) {
      int l = base + j;
      if (mrow[l] > 0) mloc[mc++] = l;
    }
    int incl2 = mc;
#pragma unroll
    for (int o = 1; o < 64; o <<= 1) {
      int v = __shfl_up(incl2, o, 64);
      if (lane >= o) incl2 += v;
    }
    if (lane == 63) wsh[w] = incl2;
    __syncthreads();
    int pre2 = 0;
#pragma unroll
    for (int i = 0; i < 4; ++i) {
      if (i < w) pre2 += wsh[i];
    }
    int excl2 = pre2 + incl2 - mc;
    for (int j = 0; j < mc; ++j) {
      int idx = excl2 + j;
      if (idx < C_) starts[b * C_ + idx] = mloc[j];
    }
  } else if (bid == B_) {
    // ---- scalars ----
    float s = 0.f, s2 = 0.f;
    for (int i = t; i < A_; i += 256) {
      float q = query[i];
      s += q;
      s2 = fmaf(q, q, s2);
    }
    sf1[t] = s;
    sf2[t] = s2;
    __syncthreads();
    for (int off = 128; off >= 1; off >>= 1) {
      if (t < off) {
        sf1[t] += sf1[t + off];
        sf2[t] += sf2[t + off];
      }
      __syncthreads();
    }
    float qsum = sf1[0], qsq = sf2[0];
    __syncthreads();
    float wv = 0.f;
    for (int i = t; i < H_; i += 256) wv += Wcls[i];
    sf1[t] = wv;
    __syncthreads();
    for (int off = 128; off >= 1; off >>= 1) {
      if (t < off) sf1[t] += sf1[t + off];
      __syncthreads();
    }
    if (t == 0) {
      float var = (qsq - qsum * qsum / (float)A_) / (float)(A_ - 1);
      ws_scal[0] = sqrtf((float)A_ * var);
      ws_scal[1] = sf1[0];
    }
  } else {
    // ---- W conversion ----
    const size_t i = ((size_t)(bid - B_ - 1) * 256 + t) * 8;
    float4 u0 = *(const float4*)(Wh + i);
    float4 u1 = *(const float4*)(Wh + i + 4);
    union { short8v v; unsigned short h[8]; } o;
    o.h[0] = f2bf(u0.x); o.h[1] = f2bf(u0.y); o.h[2] = f2bf(u0.z); o.h[3] = f2bf(u0.w);
    o.h[4] = f2bf(u1.x); o.h[5] = f2bf(u1.y); o.h[6] = f2bf(u1.z); o.h[7] = f2bf(u1.w);
    *(short8v*)(W16 + i) = o.v;
  }
}

// ============ kernel 2: kMain — MFMA probs GEMM + full-row W_cls dots ============
// bids [0, KC_BLOCKS): MFMA, idx -> (b, tile, as); 64 rows x 256 a-cols per block.
// bids [KC_BLOCKS, +KE_BLOCKS): one wave per row, d[row] = dot(input row, Wcls)
__global__ __launch_bounds__(256) void kMain(const float* __restrict__ inp,
                                             const unsigned short* __restrict__ W16,
                                             const float* __restrict__ bh,
                                             const float* __restrict__ query,
                                             const float* __restrict__ Wcls,
                                             const int* __restrict__ attn,
                                             const int* __restrict__ cnt,
                                             const int* __restrict__ list,
                                             float* __restrict__ probpart,
                                             float* __restrict__ d) {
  __shared__ __align__(16) unsigned short Xs[MT][72];    // 64x64 bf16 tile, pad->144B stride
  __shared__ __align__(16) unsigned short Ws[NTB][72];   // 256x64 bf16 tile
  __shared__ float red[2][MT];

  const int bid = blockIdx.x;
  const int t = threadIdx.x;

  if (bid >= KC_BLOCKS) {
    // ---- streaming part: one wave per row ----
    const int row = (bid - KC_BLOCKS) * 4 + (t >> 6);
    const int lane = t & 63;
    if (attn[row] == 0) return;   // masked rows handled by the MFMA part
    const float* r = inp + (size_t)row * H_;
    float acc = 0.f;
#pragma unroll
    for (int k = 0; k < 4; ++k) {
      float4 v = *(const float4*)(r + k * 256 + lane * 4);
      float4 wv = *(const float4*)(Wcls + k * 256 + lane * 4);
      acc += v.x * wv.x + v.y * wv.y + v.z * wv.z + v.w * wv.w;
    }
#pragma unroll
    for (int o = 1; o < 64; o <<= 1) acc += __shfl_xor(acc, o, 64);
    if (lane == 0) d[row] = acc;
    return;
  }

  // ---- MFMA part ----
  const int as = bid & (NSPLIT - 1);
  const int tile = (bid >> 2) & (TPB - 1);
  const int b = bid >> 5;          // NSPLIT*TPB = 32
  const int c0 = cnt[b];
  if (tile * MT >= c0) return;

  const int w = t >> 6;
  const int lane = t & 63;
  const int lg = lane >> 4;
  const int lc = lane & 15;
  const int wm = w >> 1;           // wave row-group (2)
  const int wn = w & 1;            // wave col-group (2)

  // staging decomposition
  const int xrow = t >> 2;         // [0,64)
  const int xcs = (t & 3) * 16;    // X col base (16 cols per thread)
  const int wrow = t >> 3;         // [0,32)
  const int wcs = (t & 7) * 8;     // W col base (8 cols per thread)

  const int gi = tile * MT + xrow;
  const int gidx = (gi < c0) ? gi : (c0 - 1);   // clamp; duplicate rows harmless
  const int xl = list[(size_t)b * L_ + gidx];
  const float* xptr = inp + ((size_t)(b * L_ + xl)) * H_;

  const int a0 = as * NTB;
  const unsigned short* wptr = W16 + (size_t)(a0 + wrow) * H_ + wcs;

  float4 xr0, xr1, xr2, xr3;
  short8v wr0, wr1, wr2, wr3, wr4, wr5, wr6, wr7;

#define LOADX(H0) { const float* p = xptr + (H0) + xcs; \
    xr0 = *(const float4*)p;        xr1 = *(const float4*)(p + 4); \
    xr2 = *(const float4*)(p + 8);  xr3 = *(const float4*)(p + 12); }
#define LOADW(H0) { const unsigned short* p = wptr + (H0); \
    wr0 = *(const short8v*)(p);                 wr1 = *(const short8v*)(p + 32 * H_); \
    wr2 = *(const short8v*)(p + 64 * H_);       wr3 = *(const short8v*)(p + 96 * H_); \
    wr4 = *(const short8v*)(p + 128 * H_);      wr5 = *(const short8v*)(p + 160 * H_); \
    wr6 = *(const short8v*)(p + 192 * H_);      wr7 = *(const short8v*)(p + 224 * H_); }

  float4v acc[2][8];
#pragma unroll
  for (int m = 0; m < 2; ++m)
#pragma unroll
    for (int n = 0; n < 8; ++n) acc[m][n] = (float4v){0.f, 0.f, 0.f, 0.f};

  LOADX(0);
  LOADW(0);

  for (int s = 0; s < H_ / KT; ++s) {
    __syncthreads();   // all waves done reading LDS of previous step
    // store X regs (f32 -> bf16) as 2x b128
    {
      union { short8v v; unsigned short h[8]; } o0, o1;
      o0.h[0] = f2bf(xr0.x); o0.h[1] = f2bf(xr0.y); o0.h[2] = f2bf(xr0.z); o0.h[3] = f2bf(xr0.w);
      o0.h[4] = f2bf(xr1.x); o0.h[5] = f2bf(xr1.y); o0.h[6] = f2bf(xr1.z); o0.h[7] = f2bf(xr1.w);
      o1.h[0] = f2bf(xr2.x); o1.h[1] = f2bf(xr2.y); o1.h[2] = f2bf(xr2.z); o1.h[3] = f2bf(xr2.w);
      o1.h[4] = f2bf(xr3.x); o1.h[5] = f2bf(xr3.y); o1.h[6] = f2bf(xr3.z); o1.h[7] = f2bf(xr3.w);
      *(short8v*)&Xs[xrow][xcs] = o0.v;
      *(short8v*)&Xs[xrow][xcs + 8] = o1.v;
    }
    // store W regs
    *(short8v*)&Ws[wrow][wcs] = wr0;
    *(short8v*)&Ws[wrow + 32][wcs] = wr1;
    *(short8v*)&Ws[wrow + 64][wcs] = wr2;
    *(short8v*)&Ws[wrow + 96][wcs] = wr3;
    *(short8v*)&Ws[wrow + 128][wcs] = wr4;
    *(short8v*)&Ws[wrow + 160][wcs] = wr5;
    *(short8v*)&Ws[wrow + 192][wcs] = wr6;
    *(short8v*)&Ws[wrow + 224][wcs] = wr7;
    // prefetch next step while this step computes (reg loads aren't drained by barrier)
    if (s + 1 < H_ / KT) {
      LOADX((s + 1) * KT);
      LOADW((s + 1) * KT);
    }
    __syncthreads();   // LDS tile ready
#pragma unroll
    for (int kk = 0; kk < 2; ++kk) {
      const int off = kk * 32 + lg * 8;
      short8v av0 = *(const short8v*)&Xs[wm * 32 + lc][off];
      short8v av1 = *(const short8v*)&Xs[wm * 32 + 16 + lc][off];
#pragma unroll
      for (int n = 0; n < 8; ++n) {
        short8v bv = *(const short8v*)&Ws[wn * 128 + n * 16 + lc][off];
        acc[0][n] = __builtin_amdgcn_mfma_f32_16x16x32_bf16(av0, bv, acc[0][n], 0, 0, 0);
        acc[1][n] = __builtin_amdgcn_mfma_f32_16x16x32_bf16(av1, bv, acc[1][n], 0, 0, 0);
      }
    }
  }
#undef LOADX
#undef LOADW

  // epilogue: bias + tanh + *query, reduce over a-cols
  float pp[2][4];
#pragma unroll
  for (int m = 0; m < 2; ++m)
#pragma unroll
    for (int r = 0; r < 4; ++r) pp[m][r] = 0.f;

#pragma unroll
  for (int n = 0; n < 8; ++n) {
    const int ag = a0 + wn * 128 + n * 16 + lc;
    const float q = query[ag];
    const float bb = bh[ag];
#pragma unroll
    for (int m = 0; m < 2; ++m)
#pragma unroll
      for (int r = 0; r < 4; ++r) {
        float v = acc[m][n][r] + bb;
        pp[m][r] = fmaf(tanhf(v), q, pp[m][r]);
      }
  }
  // reduce across the 16 col-lanes (within 16-lane group)
#pragma unroll
  for (int m = 0; m < 2; ++m)
#pragma unroll
    for (int r = 0; r < 4; ++r) {
#pragma unroll
      for (int o = 1; o < 16; o <<= 1)
        pp[m][r] += __shfl_xor(pp[m][r], o, 64);
    }
  __syncthreads();
  if (lc == 0) {
#pragma unroll
    for (int m = 0; m < 2; ++m)
#pragma unroll
      for (int r = 0; r < 4; ++r)
        red[wn][wm * 32 + m * 16 + lg * 4 + r] = pp[m][r];
  }
  __syncthreads();
  if (t < MT) {
    const int i = tile * MT + t;
    if (i < c0) {
      float sv = red[0][t] + red[1][t];
      int l = list[(size_t)b * L_ + i];
      probpart[((size_t)as * B_ + b) * L_ + l] = sv;
    }
  }
}

// ============ kernel 3: kT — softmax scalars + segment sums + 80 outputs ============
__global__ __launch_bounds__(256) void kT(const int* __restrict__ cnt,
                                          const int* __restrict__ list,
                                          const float* __restrict__ probpart,
                                          const float* __restrict__ ws_scal,
                                          const float* __restrict__ d,
                                          const int* __restrict__ starts,
                                          const int* __restrict__ endv,
                                          const float* __restrict__ bcls,
                                          float* __restrict__ out) {
  __shared__ float lg[L_];
  __shared__ float red[256];
  const int b = blockIdx.x;
  const int t = threadIdx.x;
  const float denom = ws_scal[0];
  const int c0 = cnt[b];

  // logits at masked positions; attended logits are exactly 0
  float mx = 0.0f;  // 0 participates (attended positions exist: valid length >= 64)
  for (int i = t; i < c0; i += 256) {
    int l = list[(size_t)b * L_ + i];
    float s = probpart[((size_t)0 * B_ + b) * L_ + l]
            + probpart[((size_t)1 * B_ + b) * L_ + l]
            + probpart[((size_t)2 * B_ + b) * L_ + l]
            + probpart[((size_t)3 * B_ + b) * L_ + l];
    float v = -1000.0f * (s / denom);
    lg[i] = v;
    mx = fmaxf(mx, v);
  }
  red[t] = mx;
  __syncthreads();
  for (int off = 128; off >= 1; off >>= 1) {
    if (t < off) red[t] = fmaxf(red[t], red[t + off]);
    __syncthreads();
  }
  const float m = red[0];
  __syncthreads();

  float zs = 0.f;
  for (int i = t; i < c0; i += 256) zs += expf(lg[i] - m);
  if (t == 0) zs += (float)(L_ - c0) * expf(-m);
  red[t] = zs;
  __syncthreads();
  for (int off = 128; off >= 1; off >>= 1) {
    if (t < off) red[t] += red[t + off];
    __syncthreads();
  }
  const float Z = red[0];
  __syncthreads();
  const float att0 = expf(-m) / Z;   // att value at every attended position

  for (int c = 0; c < C_; ++c) {
    const int st = starts[b * C_ + c];
    const int bound = (c < C_ - 1) ? (starts[b * C_ + c + 1] - 1) : (endv[b] - 1);
    const int lo = st + 1;
    const int hi = bound;
    float a = 0.f;
    for (int l = lo + t; l < hi; l += 256) a += d[(size_t)b * L_ + l];
    red[t] = a;
    __syncthreads();
    for (int off = 128; off >= 1; off >>= 1) {
      if (t < off) red[t] += red[t + off];
      __syncthreads();
    }
    if (t == 0) {
      int count = hi - lo;
      if (count < 0) count = 0;
      out[b * C_ + c] = red[0] + ws_scal[1] * att0 * (float)count + bcls[0];
    }
    __syncthreads();
  }
}

extern "C" void kernel_launch(void* const* d_in, const int* in_sizes, int n_in,
                              void* d_out, int out_size, void* d_ws, size_t ws_size,
                              hipStream_t stream) {
  const float* inp   = (const float*)d_in[0];
  const int*   attn  = (const int*)d_in[1];
  const int*   mlm   = (const int*)d_in[2];
  const float* Wh    = (const float*)d_in[3];
  const float* bh    = (const float*)d_in[4];
  const float* query = (const float*)d_in[5];
  const float* Wcls  = (const float*)d_in[6];
  const float* bcls  = (const float*)d_in[7];
  float* out = (float*)d_out;

  char* ws = (char*)d_ws;
  float*          ws_scal = (float*)(ws + OFF_SCAL);
  int*            endv    = (int*)(ws + OFF_END);
  int*            cnt     = (int*)(ws + OFF_CNT);
  int*            starts  = (int*)(ws + OFF_STARTS);
  int*            list    = (int*)(ws + OFF_LIST);
  unsigned short* W16     = (unsigned short*)(ws + OFF_W16);
  float*          probpart= (float*)(ws + OFF_PP);
  float*          dvec    = (float*)(ws + OFF_D);

  hipLaunchKernelGGL(kWA, dim3(B_ + 1 + KW_BLOCKS), dim3(256), 0, stream,
                     attn, mlm, query, Wcls, Wh, ws_scal, endv, cnt, starts, list, W16);
  hipLaunchKernelGGL(kMain, dim3(KC_BLOCKS + KE_BLOCKS), dim3(256), 0, stream,
                     inp, W16, bh, query, Wcls, attn, cnt, list, probpart, dvec);
  hipLaunchKernelGGL(kT, dim3(B_), dim3(256), 0, stream,
                     cnt, list, probpart, ws_scal, dvec, starts, endv, bcls, out);
}